// Round 7
// baseline (2545.026 us; speedup 1.0000x reference)
//
#include <hip/hip_runtime.h>

// LSTM, B=128, T=256 (255 steps), H=512, V=128, C=128.  OUTPUT = FLOAT32.
// 8 groups x 16 batch rows; 32 WGs/group; WG w owns h-cols [16w,16w+16).
// Wave v (of 4) = K-slice ks in [4v,4v+4) for ALL 4 gates.
// fp32-equivalent math: W and h each split into 3 bf16 planes; 6 cross-term
// MFMAs. h exchanged via agent-scope atomic u32 load/store (tester-verified
// in round 6). Rounds 2-6 produced bit-identical (correct) h; the only bug
// was writing bf16 into the float32 output buffer.
// Co-residency: 256 blocks, 1 per CU, plain launch.

typedef __attribute__((ext_vector_type(8))) short short8;
typedef __attribute__((ext_vector_type(4))) float f32x4;
typedef __attribute__((ext_vector_type(4))) unsigned int u32x4;

#define NGROUPS 8
#define WGS_PER_GROUP 32
#define HDIM 512
#define TT 256
#define NSTEPS 255
#define CDIM 128
#define PLANE 8192        // shorts per plane: 16 ks * 64 lanes * 8 e
#define PGSTRIDE 24576    // shorts per (parity,group): 3 planes
#define PLANE_W 4096      // u32 words per plane

__device__ unsigned short g_hbuf[2 * NGROUPS * PGSTRIDE];  // 768 KB
__device__ unsigned int g_flags[NGROUPS];

static __device__ __forceinline__ unsigned short f32_to_bf16(float f) {
  unsigned int u = __builtin_bit_cast(unsigned int, f);
  u += 0x7fffu + ((u >> 16) & 1u);   // RNE
  return (unsigned short)(u >> 16);
}
static __device__ __forceinline__ float bf16_to_f32(unsigned short s) {
  unsigned int u = ((unsigned int)s) << 16;
  return __builtin_bit_cast(float, u);
}
static __device__ __forceinline__ unsigned int coh_load(const unsigned int* p) {
  return __hip_atomic_load(p, __ATOMIC_RELAXED, __HIP_MEMORY_SCOPE_AGENT);
}
static __device__ __forceinline__ void coh_store(unsigned int* p, unsigned int v) {
  __hip_atomic_store(p, v, __ATOMIC_RELAXED, __HIP_MEMORY_SCOPE_AGENT);
}

__global__ __launch_bounds__(256, 1) void lstm_persistent(
    const int* __restrict__ x,
    const float* __restrict__ Wxg, const float* __restrict__ Whg,
    const float* __restrict__ Wxi, const float* __restrict__ Whi,
    const float* __restrict__ Wxf, const float* __restrict__ Whf,
    const float* __restrict__ Wxo, const float* __restrict__ Who,
    const float* __restrict__ Whp,
    const float* __restrict__ bg, const float* __restrict__ bi,
    const float* __restrict__ bf, const float* __restrict__ bo,
    const float* __restrict__ bp,
    float* __restrict__ out)
{
  const int bid = blockIdx.x;
  const int g = bid & 7;
  const int w = bid >> 3;
  const int tid = threadIdx.x;
  const int wave = tid >> 6;       // K-slice owner: ks in [4*wave, 4*wave+4)
  const int lane = tid & 63;
  const int lane15 = lane & 15;
  const int lanehi = lane >> 4;

  __shared__ float part[4][4][16][16];          // [wave][gate][row][col] 16KB
  __shared__ __align__(16) unsigned short hfin[3 * PLANE];  // epilogue, 48KB

  // ---- one-time: W_h fragments, 3-way bf16 split, this wave's 4 k-steps ----
  const float* Whs[4] = {Whg, Whi, Whf, Who};
  const int bcol = (w << 4) + lane15;
  short8 wf[4][4][3];   // [gate][ksl][plane]
#pragma unroll
  for (int gate = 0; gate < 4; ++gate) {
    const float* Wh = Whs[gate];
#pragma unroll
    for (int ksl = 0; ksl < 4; ++ksl) {
      const int ksg = (wave << 2) + ksl;
      short8 s0, s1, s2;
#pragma unroll
      for (int e = 0; e < 8; ++e) {
        float v = Wh[(ksg * 32 + lanehi * 8 + e) * HDIM + bcol];
        unsigned short a = f32_to_bf16(v);
        float r1 = v - bf16_to_f32(a);
        unsigned short b = f32_to_bf16(r1);
        float r2 = r1 - bf16_to_f32(b);
        unsigned short c = f32_to_bf16(r2);
        s0[e] = (short)a; s1[e] = (short)b; s2[e] = (short)c;
      }
      wf[gate][ksl][0] = s0; wf[gate][ksl][1] = s1; wf[gate][ksl][2] = s2;
    }
  }

  // ---- elementwise mapping: thread -> (batch row, h col) ----
  const int brow = tid >> 4;
  const int jl = tid & 15;
  const int j = (w << 4) + jl;
  const int rowg = g * 16 + brow;
  const float bgv = bg[j], biv = bi[j], bfv = bf[j], bov = bo[j];
  const int woff = ((j >> 5) << 9) + (((((j >> 3) & 3) << 4) + brow) << 3) + (j & 7);

  float creg = 0.0f;

  for (int t = 0; t < NSTEPS; ++t) {
    if (t > 0 && tid == 0) {
      const unsigned int tgt = (unsigned int)(WGS_PER_GROUP * t);
      while (__hip_atomic_load(g_flags + g, __ATOMIC_ACQUIRE,
                               __HIP_MEMORY_SCOPE_AGENT) < tgt) {
        __builtin_amdgcn_s_sleep(2);
      }
    }
    __syncthreads();

    // ---- token-gather contributions ----
    const int idx = x[rowg * TT + t];
    const float xgv = Wxg[idx * HDIM + j];
    const float xiv = Wxi[idx * HDIM + j];
    const float xfv = Wxf[idx * HDIM + j];
    const float xov = Wxo[idx * HDIM + j];

    // ---- load A fragments (coherence-point atomics) & MFMA ----
    f32x4 acc[4] = {{0.f,0.f,0.f,0.f},{0.f,0.f,0.f,0.f},
                    {0.f,0.f,0.f,0.f},{0.f,0.f,0.f,0.f}};
    if (t > 0) {
      const unsigned int* srcw = (const unsigned int*)
          (g_hbuf + ((size_t)((t & 1) * NGROUPS + g)) * PGSTRIDE);
      u32x4 q0[4], q1[4], q2[4];
#pragma unroll
      for (int ksl = 0; ksl < 4; ++ksl) {
        const int wb = ((wave << 2) + ksl) * 256 + lane * 4;  // u32 idx in plane
#pragma unroll
        for (int u = 0; u < 4; ++u) {
          q0[ksl][u] = coh_load(srcw + wb + u);
          q1[ksl][u] = coh_load(srcw + PLANE_W + wb + u);
          q2[ksl][u] = coh_load(srcw + 2 * PLANE_W + wb + u);
        }
      }
#pragma unroll
      for (int ksl = 0; ksl < 4; ++ksl) {
        const short8 a0 = __builtin_bit_cast(short8, q0[ksl]);
        const short8 a1 = __builtin_bit_cast(short8, q1[ksl]);
        const short8 a2 = __builtin_bit_cast(short8, q2[ksl]);
#pragma unroll
        for (int gate = 0; gate < 4; ++gate) {
          acc[gate] = __builtin_amdgcn_mfma_f32_16x16x32_bf16(a0, wf[gate][ksl][0], acc[gate], 0, 0, 0);
          acc[gate] = __builtin_amdgcn_mfma_f32_16x16x32_bf16(a0, wf[gate][ksl][1], acc[gate], 0, 0, 0);
          acc[gate] = __builtin_amdgcn_mfma_f32_16x16x32_bf16(a1, wf[gate][ksl][0], acc[gate], 0, 0, 0);
          acc[gate] = __builtin_amdgcn_mfma_f32_16x16x32_bf16(a0, wf[gate][ksl][2], acc[gate], 0, 0, 0);
          acc[gate] = __builtin_amdgcn_mfma_f32_16x16x32_bf16(a1, wf[gate][ksl][1], acc[gate], 0, 0, 0);
          acc[gate] = __builtin_amdgcn_mfma_f32_16x16x32_bf16(a2, wf[gate][ksl][0], acc[gate], 0, 0, 0);
        }
      }
    }
    {
      const int crow = lanehi << 2;   // C/D: row=(lane>>4)*4+r, col=lane&15
#pragma unroll
      for (int gate = 0; gate < 4; ++gate)
#pragma unroll
        for (int r = 0; r < 4; ++r)
          part[wave][gate][crow + r][lane15] = acc[gate][r];
    }
    __syncthreads();

    // ---- elementwise: reduce partials, gates, cell, hidden ----
    const float pg = part[0][0][brow][jl] + part[1][0][brow][jl] +
                     part[2][0][brow][jl] + part[3][0][brow][jl] + xgv + bgv;
    const float pi = part[0][1][brow][jl] + part[1][1][brow][jl] +
                     part[2][1][brow][jl] + part[3][1][brow][jl] + xiv + biv;
    const float pf = part[0][2][brow][jl] + part[1][2][brow][jl] +
                     part[2][2][brow][jl] + part[3][2][brow][jl] + xfv + bfv;
    const float po = part[0][3][brow][jl] + part[1][3][brow][jl] +
                     part[2][3][brow][jl] + part[3][3][brow][jl] + xov + bov;
    const float gv = tanhf(pg);
    const float iv = 1.0f / (1.0f + expf(-pi));
    const float fv = 1.0f / (1.0f + expf(-pf));
    const float ov = 1.0f / (1.0f + expf(-po));
    creg = gv * iv + creg * fv;
    const float hv = tanhf(creg) * ov;

    // 3-way split; pack even/odd-neighbor shorts into u32; coherent store
    const unsigned short h0 = f32_to_bf16(hv);
    const float r1 = hv - bf16_to_f32(h0);
    const unsigned short h1 = f32_to_bf16(r1);
    const float r2 = r1 - bf16_to_f32(h1);
    const unsigned short h2 = f32_to_bf16(r2);
    const unsigned int pa = (unsigned int)h0 | ((unsigned int)h1 << 16);
    const unsigned int pb = (unsigned int)h2;
    const unsigned int na = (unsigned int)__shfl_xor((int)pa, 1);
    const unsigned int nb = (unsigned int)__shfl_xor((int)pb, 1);
    if (!(jl & 1)) {
      unsigned short* dstb =
          g_hbuf + ((size_t)(((t + 1) & 1) * NGROUPS + g)) * PGSTRIDE;
      coh_store((unsigned int*)(dstb + woff),
                (pa & 0xffffu) | ((na & 0xffffu) << 16));
      coh_store((unsigned int*)(dstb + PLANE + woff),
                (pa >> 16) | (na & 0xffff0000u));
      coh_store((unsigned int*)(dstb + 2 * PLANE + woff),
                (pb & 0xffffu) | ((nb & 0xffffu) << 16));
    }
    __syncthreads();   // all waves' stores drained (vmcnt 0) before flag
    if (tid == 0) {
      __hip_atomic_fetch_add(g_flags + g, 1u, __ATOMIC_RELEASE,
                             __HIP_MEMORY_SCOPE_AGENT);
    }
  }

  // ---- epilogue: out = h^255 @ W_hp + b_p  (FLOAT32 output) ----
  if (tid == 0) {
    const unsigned int tgt = (unsigned int)(WGS_PER_GROUP * NSTEPS);
    while (__hip_atomic_load(g_flags + g, __ATOMIC_ACQUIRE,
                             __HIP_MEMORY_SCOPE_AGENT) < tgt) {
      __builtin_amdgcn_s_sleep(2);
    }
  }
  __syncthreads();
  {
    const unsigned int* srcw = (const unsigned int*)
        (g_hbuf + ((size_t)((NSTEPS & 1) * NGROUPS + g)) * PGSTRIDE);
    unsigned int* dstw = (unsigned int*)hfin;
    for (int i = tid; i < 3 * PLANE_W; i += 256) dstw[i] = coh_load(srcw + i);
  }
  __syncthreads();
  {
    const int bq = tid >> 4;
    const int q = tid & 15;
    const int cloc = q >> 2;
    const int ksl2 = q & 3;
    const int cc = (w << 2) + cloc;
    float sum = 0.0f;
    for (int k = ksl2 * 128; k < ksl2 * 128 + 128; ++k) {
      const int off = ((k >> 5) << 9) + (((((k >> 3) & 3) << 4) + bq) << 3) + (k & 7);
      const float hvf = bf16_to_f32(hfin[off]) + bf16_to_f32(hfin[PLANE + off]) +
                        bf16_to_f32(hfin[2 * PLANE + off]);
      sum += hvf * Whp[k * CDIM + cc];
    }
    float* gb = &part[0][0][0][0];
    gb[tid] = sum;
    __syncthreads();
    if (ksl2 == 0) {
      const float res = gb[tid] + gb[tid + 1] + gb[tid + 2] + gb[tid + 3] + bp[cc];
      out[(g * 16 + bq) * CDIM + cc] = res;   // fp32 store
    }
  }
}

extern "C" void kernel_launch(void* const* d_in, const int* in_sizes, int n_in,
                              void* d_out, int out_size, void* d_ws, size_t ws_size,
                              hipStream_t stream) {
  (void)in_sizes; (void)n_in; (void)out_size; (void)d_ws; (void)ws_size;
  const int* x = (const int*)d_in[0];
  const float* Wxg = (const float*)d_in[1];
  const float* Whg = (const float*)d_in[2];
  const float* Wxi = (const float*)d_in[3];
  const float* Whi = (const float*)d_in[4];
  const float* Wxf = (const float*)d_in[5];
  const float* Whf = (const float*)d_in[6];
  const float* Wxo = (const float*)d_in[7];
  const float* Who = (const float*)d_in[8];
  const float* Whp = (const float*)d_in[9];
  const float* bg = (const float*)d_in[10];
  const float* bi = (const float*)d_in[11];
  const float* bf = (const float*)d_in[12];
  const float* bo = (const float*)d_in[13];
  const float* bp = (const float*)d_in[14];
  float* out = (float*)d_out;

  // zero the per-launch flag counters (device-global symbol)
  void* flags_dev = nullptr;
  hipGetSymbolAddress(&flags_dev, HIP_SYMBOL(g_flags));
  hipMemsetAsync(flags_dev, 0, sizeof(unsigned int) * NGROUPS, stream);

  lstm_persistent<<<dim3(256), dim3(256), 0, stream>>>(
      x, Wxg, Whg, Wxi, Whi, Wxf, Whf, Wxo, Who, Whp,
      bg, bi, bf, bo, bp, out);
}

// Round 8
// 2026.613 us; speedup vs baseline: 1.2558x; 1.2558x over previous
//
#include <hip/hip_runtime.h>

// LSTM, B=128, T=256 (255 steps), H=512, V=128, C=128.  OUTPUT = FLOAT32.
// 8 groups x 16 batch rows; 32 WGs/group; WG w owns h-cols [16w,16w+16).
// Wave v (of 4) = K-slice ks in [4v,4v+4) for ALL 4 gates.
// Round 8: 3-term split (W,h in 2 bf16 planes each; err << threshold, proven
// r2-vs-r4 bit-identical), u64 packed exchange (both planes in one atomic),
// fast transcendentals, x-gather prefetched before the flag wait.
// h exchanged via agent-scope atomic u64 load/store (protocol tester-verified
// round 6). Co-residency: 256 blocks, 1 per CU, plain launch.

typedef __attribute__((ext_vector_type(8))) short short8;
typedef __attribute__((ext_vector_type(4))) float f32x4;
typedef __attribute__((ext_vector_type(4))) unsigned int u32x4;

#define NGROUPS 8
#define WGS_PER_GROUP 32
#define HDIM 512
#define TT 256
#define NSTEPS 255
#define CDIM 128
#define PGQ 4096          // u64 words per (parity,group): 16 ks * 64 lane * 4

__device__ unsigned long long g_hbuf[2 * NGROUPS * PGQ];  // 512 KB
__device__ unsigned int g_flags[NGROUPS];

static __device__ __forceinline__ unsigned short f32_to_bf16(float f) {
  unsigned int u = __builtin_bit_cast(unsigned int, f);
  u += 0x7fffu + ((u >> 16) & 1u);   // RNE
  return (unsigned short)(u >> 16);
}
static __device__ __forceinline__ float bf16_to_f32(unsigned short s) {
  unsigned int u = ((unsigned int)s) << 16;
  return __builtin_bit_cast(float, u);
}
static __device__ __forceinline__ float fast_sigmoid(float v) {
  return __builtin_amdgcn_rcpf(1.0f + __expf(-v));
}
static __device__ __forceinline__ float fast_tanh(float v) {
  return 1.0f - 2.0f * __builtin_amdgcn_rcpf(1.0f + __expf(2.0f * v));
}

__global__ __launch_bounds__(256, 1) void lstm_persistent(
    const int* __restrict__ x,
    const float* __restrict__ Wxg, const float* __restrict__ Whg,
    const float* __restrict__ Wxi, const float* __restrict__ Whi,
    const float* __restrict__ Wxf, const float* __restrict__ Whf,
    const float* __restrict__ Wxo, const float* __restrict__ Who,
    const float* __restrict__ Whp,
    const float* __restrict__ bg, const float* __restrict__ bi,
    const float* __restrict__ bf, const float* __restrict__ bo,
    const float* __restrict__ bp,
    float* __restrict__ out)
{
  const int bid = blockIdx.x;
  const int g = bid & 7;
  const int w = bid >> 3;
  const int tid = threadIdx.x;
  const int wave = tid >> 6;       // K-slice owner: ks in [4*wave, 4*wave+4)
  const int lane = tid & 63;
  const int lane15 = lane & 15;
  const int lanehi = lane >> 4;

  __shared__ float part[4][4][16][16];               // [wave][gate][row][col] 16KB
  __shared__ __align__(16) unsigned long long hfinq[PGQ];  // epilogue, 32KB

  // ---- one-time: W_h fragments, 2-plane bf16 split, this wave's 4 k-steps ----
  const float* Whs[4] = {Whg, Whi, Whf, Who};
  const int bcol = (w << 4) + lane15;
  short8 wf[4][4][2];   // [gate][ksl][plane], 128 VGPR
#pragma unroll
  for (int gate = 0; gate < 4; ++gate) {
    const float* Wh = Whs[gate];
#pragma unroll
    for (int ksl = 0; ksl < 4; ++ksl) {
      const int ksg = (wave << 2) + ksl;
      short8 s0, s1;
#pragma unroll
      for (int e = 0; e < 8; ++e) {
        float v = Wh[(ksg * 32 + lanehi * 8 + e) * HDIM + bcol];
        unsigned short a = f32_to_bf16(v);
        unsigned short b = f32_to_bf16(v - bf16_to_f32(a));
        s0[e] = (short)a; s1[e] = (short)b;
      }
      wf[gate][ksl][0] = s0; wf[gate][ksl][1] = s1;
    }
  }

  // ---- elementwise mapping: thread -> (batch row, h col) ----
  const int brow = tid >> 4;
  const int jl = tid & 15;
  const int j = (w << 4) + jl;
  const int rowg = g * 16 + brow;
  const float bgv = bg[j], biv = bi[j], bfv = bf[j], bov = bo[j];
  // u64 pair-index for h cols (j,j+1), row brow (even-j threads store)
  const int pidx = ((j >> 5) << 8) + ((((j >> 3) & 3) << 4) + brow) * 4 + ((j & 7) >> 1);

  float creg = 0.0f;

  for (int t = 0; t < NSTEPS; ++t) {
    // ---- x-gather issued BEFORE the wait (flies during the spin) ----
    const int idx = x[rowg * TT + t];
    const float xgv = Wxg[idx * HDIM + j];
    const float xiv = Wxi[idx * HDIM + j];
    const float xfv = Wxf[idx * HDIM + j];
    const float xov = Wxo[idx * HDIM + j];

    if (t > 0 && tid == 0) {
      const unsigned int tgt = (unsigned int)(WGS_PER_GROUP * t);
      while (__hip_atomic_load(g_flags + g, __ATOMIC_ACQUIRE,
                               __HIP_MEMORY_SCOPE_AGENT) < tgt) {
        __builtin_amdgcn_s_sleep(1);
      }
    }
    __syncthreads();

    // ---- load A fragments (u64 coherence-point atomics) & MFMA ----
    f32x4 acc[4] = {{0.f,0.f,0.f,0.f},{0.f,0.f,0.f,0.f},
                    {0.f,0.f,0.f,0.f},{0.f,0.f,0.f,0.f}};
    if (t > 0) {
      const unsigned long long* srcq =
          g_hbuf + ((size_t)((t & 1) * NGROUPS + g)) * PGQ;
      unsigned long long q[4][4];
#pragma unroll
      for (int ksl = 0; ksl < 4; ++ksl) {
        const int base = ((wave << 2) + ksl) * 256 + (lane << 2);
#pragma unroll
        for (int u = 0; u < 4; ++u)
          q[ksl][u] = __hip_atomic_load(srcq + base + u, __ATOMIC_RELAXED,
                                        __HIP_MEMORY_SCOPE_AGENT);
      }
#pragma unroll
      for (int ksl = 0; ksl < 4; ++ksl) {
        u32x4 lo, hi;
#pragma unroll
        for (int u = 0; u < 4; ++u) {
          lo[u] = (unsigned int)q[ksl][u];
          hi[u] = (unsigned int)(q[ksl][u] >> 32);
        }
        const short8 a0 = __builtin_bit_cast(short8, lo);
        const short8 a1 = __builtin_bit_cast(short8, hi);
#pragma unroll
        for (int gate = 0; gate < 4; ++gate) {
          acc[gate] = __builtin_amdgcn_mfma_f32_16x16x32_bf16(a0, wf[gate][ksl][0], acc[gate], 0, 0, 0);
          acc[gate] = __builtin_amdgcn_mfma_f32_16x16x32_bf16(a0, wf[gate][ksl][1], acc[gate], 0, 0, 0);
          acc[gate] = __builtin_amdgcn_mfma_f32_16x16x32_bf16(a1, wf[gate][ksl][0], acc[gate], 0, 0, 0);
        }
      }
    }
    {
      const int crow = lanehi << 2;   // C/D: row=(lane>>4)*4+r, col=lane&15
#pragma unroll
      for (int gate = 0; gate < 4; ++gate)
#pragma unroll
        for (int r = 0; r < 4; ++r)
          part[wave][gate][crow + r][lane15] = acc[gate][r];
    }
    __syncthreads();

    // ---- elementwise: reduce partials, gates, cell, hidden ----
    const float pg = part[0][0][brow][jl] + part[1][0][brow][jl] +
                     part[2][0][brow][jl] + part[3][0][brow][jl] + xgv + bgv;
    const float pi = part[0][1][brow][jl] + part[1][1][brow][jl] +
                     part[2][1][brow][jl] + part[3][1][brow][jl] + xiv + biv;
    const float pf = part[0][2][brow][jl] + part[1][2][brow][jl] +
                     part[2][2][brow][jl] + part[3][2][brow][jl] + xfv + bfv;
    const float po = part[0][3][brow][jl] + part[1][3][brow][jl] +
                     part[2][3][brow][jl] + part[3][3][brow][jl] + xov + bov;
    const float gv = fast_tanh(pg);
    const float iv = fast_sigmoid(pi);
    const float fv = fast_sigmoid(pf);
    const float ov = fast_sigmoid(po);
    creg = gv * iv + creg * fv;
    const float hv = fast_tanh(creg) * ov;

    // 2-plane split; pack (j,j+1)x(plane0,plane1) into one u64; atomic store
    const unsigned short h0 = f32_to_bf16(hv);
    const unsigned short h1 = f32_to_bf16(hv - bf16_to_f32(h0));
    const unsigned int pa = (unsigned int)h0 | ((unsigned int)h1 << 16);
    const unsigned int na = (unsigned int)__shfl_xor((int)pa, 1);
    if (!(jl & 1)) {
      unsigned long long* dstq =
          g_hbuf + ((size_t)(((t + 1) & 1) * NGROUPS + g)) * PGQ;
      const unsigned int w0 = (pa & 0xffffu) | ((na & 0xffffu) << 16);   // plane0
      const unsigned int w1 = (pa >> 16) | (na & 0xffff0000u);           // plane1
      const unsigned long long v =
          (unsigned long long)w0 | ((unsigned long long)w1 << 32);
      __hip_atomic_store(dstq + pidx, v, __ATOMIC_RELAXED,
                         __HIP_MEMORY_SCOPE_AGENT);
    }
    __syncthreads();   // all waves' stores drained (vmcnt 0) before flag
    if (tid == 0) {
      __hip_atomic_fetch_add(g_flags + g, 1u, __ATOMIC_RELEASE,
                             __HIP_MEMORY_SCOPE_AGENT);
    }
  }

  // ---- epilogue: out = h^255 @ W_hp + b_p  (FLOAT32 output) ----
  if (tid == 0) {
    const unsigned int tgt = (unsigned int)(WGS_PER_GROUP * NSTEPS);
    while (__hip_atomic_load(g_flags + g, __ATOMIC_ACQUIRE,
                             __HIP_MEMORY_SCOPE_AGENT) < tgt) {
      __builtin_amdgcn_s_sleep(1);
    }
  }
  __syncthreads();
  {
    const unsigned long long* srcq =
        g_hbuf + ((size_t)((NSTEPS & 1) * NGROUPS + g)) * PGQ;
    for (int i = tid; i < PGQ; i += 256)
      hfinq[i] = __hip_atomic_load(srcq + i, __ATOMIC_RELAXED,
                                   __HIP_MEMORY_SCOPE_AGENT);
  }
  __syncthreads();
  {
    const int bq = tid >> 4;
    const int q = tid & 15;
    const int cloc = q >> 2;
    const int ksl2 = q & 3;
    const int cc = (w << 2) + cloc;
    float sum = 0.0f;
    for (int k = ksl2 * 128; k < ksl2 * 128 + 128; ++k) {
      const int pk = ((k >> 5) << 8) + ((((k >> 3) & 3) << 4) + bq) * 4 + ((k & 7) >> 1);
      const unsigned long long qv = hfinq[pk];
      const unsigned int w0 = (unsigned int)qv;
      const unsigned int w1 = (unsigned int)(qv >> 32);
      const unsigned short s0 = (k & 1) ? (unsigned short)(w0 >> 16)
                                        : (unsigned short)(w0 & 0xffffu);
      const unsigned short s1 = (k & 1) ? (unsigned short)(w1 >> 16)
                                        : (unsigned short)(w1 & 0xffffu);
      const float hvf = bf16_to_f32(s0) + bf16_to_f32(s1);
      sum += hvf * Whp[k * CDIM + cc];
    }
    float* gb = &part[0][0][0][0];
    gb[tid] = sum;
    __syncthreads();
    if (ksl2 == 0) {
      const float res = gb[tid] + gb[tid + 1] + gb[tid + 2] + gb[tid + 3] + bp[cc];
      out[(g * 16 + bq) * CDIM + cc] = res;
    }
  }
}

extern "C" void kernel_launch(void* const* d_in, const int* in_sizes, int n_in,
                              void* d_out, int out_size, void* d_ws, size_t ws_size,
                              hipStream_t stream) {
  (void)in_sizes; (void)n_in; (void)out_size; (void)d_ws; (void)ws_size;
  const int* x = (const int*)d_in[0];
  const float* Wxg = (const float*)d_in[1];
  const float* Whg = (const float*)d_in[2];
  const float* Wxi = (const float*)d_in[3];
  const float* Whi = (const float*)d_in[4];
  const float* Wxf = (const float*)d_in[5];
  const float* Whf = (const float*)d_in[6];
  const float* Wxo = (const float*)d_in[7];
  const float* Who = (const float*)d_in[8];
  const float* Whp = (const float*)d_in[9];
  const float* bg = (const float*)d_in[10];
  const float* bi = (const float*)d_in[11];
  const float* bf = (const float*)d_in[12];
  const float* bo = (const float*)d_in[13];
  const float* bp = (const float*)d_in[14];
  float* out = (float*)d_out;

  void* flags_dev = nullptr;
  hipGetSymbolAddress(&flags_dev, HIP_SYMBOL(g_flags));
  hipMemsetAsync(flags_dev, 0, sizeof(unsigned int) * NGROUPS, stream);

  lstm_persistent<<<dim3(256), dim3(256), 0, stream>>>(
      x, Wxg, Whg, Wxi, Whi, Wxf, Whf, Wxo, Who, Whp,
      bg, bi, bf, bo, bp, out);
}

// Round 9
// 713.111 us; speedup vs baseline: 3.5689x; 2.8419x over previous
//
#include <hip/hip_runtime.h>

// LSTM, B=128, T=256 (255 steps), H=512, V=128, C=128.  OUTPUT = FLOAT32.
// 8 groups x 16 batch rows; 32 WGs/group; WG w owns h-cols [16w,16w+16).
// Wave v (of 4) = K-slice ks in [4v,4v+4) for ALL 4 gates.
// Round 9 (sync overhaul): per-WG flag SLOTS (relaxed atomic stores, 64B
// apart -- no 32-way RMW serialization) + per-wave RELAXED vector polling
// (no acquire -> no per-poll cache invalidates; data visibility rides on
// sc-flagged coherence-point atomics, the exact pattern the round-6 tester
// verified). part[] padded to kill LDS bank conflicts.
// Co-residency: 256 blocks, 1 per CU, plain launch.

typedef __attribute__((ext_vector_type(8))) short short8;
typedef __attribute__((ext_vector_type(4))) float f32x4;
typedef __attribute__((ext_vector_type(4))) unsigned int u32x4;

#define NGROUPS 8
#define WGS_PER_GROUP 32
#define HDIM 512
#define TT 256
#define NSTEPS 255
#define CDIM 128
#define PGQ 4096          // u64 words per (parity,group): 16 ks * 64 lane * 4
#define FSTRIDE 16        // u32 words per flag slot (64 B)

__device__ unsigned long long g_hbuf[2 * NGROUPS * PGQ];  // 512 KB
__device__ unsigned int g_flags[NGROUPS * WGS_PER_GROUP * FSTRIDE];  // 16 KB

static __device__ __forceinline__ unsigned short f32_to_bf16(float f) {
  unsigned int u = __builtin_bit_cast(unsigned int, f);
  u += 0x7fffu + ((u >> 16) & 1u);   // RNE
  return (unsigned short)(u >> 16);
}
static __device__ __forceinline__ float bf16_to_f32(unsigned short s) {
  unsigned int u = ((unsigned int)s) << 16;
  return __builtin_bit_cast(float, u);
}
static __device__ __forceinline__ float fast_sigmoid(float v) {
  return __builtin_amdgcn_rcpf(1.0f + __expf(-v));
}
static __device__ __forceinline__ float fast_tanh(float v) {
  return 1.0f - 2.0f * __builtin_amdgcn_rcpf(1.0f + __expf(2.0f * v));
}

__global__ __launch_bounds__(256, 1) void lstm_persistent(
    const int* __restrict__ x,
    const float* __restrict__ Wxg, const float* __restrict__ Whg,
    const float* __restrict__ Wxi, const float* __restrict__ Whi,
    const float* __restrict__ Wxf, const float* __restrict__ Whf,
    const float* __restrict__ Wxo, const float* __restrict__ Who,
    const float* __restrict__ Whp,
    const float* __restrict__ bg, const float* __restrict__ bi,
    const float* __restrict__ bf, const float* __restrict__ bo,
    const float* __restrict__ bp,
    float* __restrict__ out)
{
  const int bid = blockIdx.x;
  const int g = bid & 7;
  const int w = bid >> 3;
  const int tid = threadIdx.x;
  const int wave = tid >> 6;       // K-slice owner: ks in [4*wave, 4*wave+4)
  const int lane = tid & 63;
  const int lane15 = lane & 15;
  const int lanehi = lane >> 4;

  __shared__ float part[4][4][16][17];               // padded: no bank conflicts
  __shared__ __align__(16) unsigned long long hfinq[PGQ];  // epilogue, 32KB

  // ---- one-time: W_h fragments, 2-plane bf16 split, this wave's 4 k-steps ----
  const float* Whs[4] = {Whg, Whi, Whf, Who};
  const int bcol = (w << 4) + lane15;
  short8 wf[4][4][2];   // [gate][ksl][plane], 128 VGPR
#pragma unroll
  for (int gate = 0; gate < 4; ++gate) {
    const float* Wh = Whs[gate];
#pragma unroll
    for (int ksl = 0; ksl < 4; ++ksl) {
      const int ksg = (wave << 2) + ksl;
      short8 s0, s1;
#pragma unroll
      for (int e = 0; e < 8; ++e) {
        float v = Wh[(ksg * 32 + lanehi * 8 + e) * HDIM + bcol];
        unsigned short a = f32_to_bf16(v);
        unsigned short b = f32_to_bf16(v - bf16_to_f32(a));
        s0[e] = (short)a; s1[e] = (short)b;
      }
      wf[gate][ksl][0] = s0; wf[gate][ksl][1] = s1;
    }
  }

  // ---- elementwise mapping: thread -> (batch row, h col) ----
  const int brow = tid >> 4;
  const int jl = tid & 15;
  const int j = (w << 4) + jl;
  const int rowg = g * 16 + brow;
  const float bgv = bg[j], biv = bi[j], bfv = bf[j], bov = bo[j];
  // u64 pair-index for h cols (j,j+1), row brow (even-j threads store)
  const int pidx = ((j >> 5) << 8) + ((((j >> 3) & 3) << 4) + brow) * 4 + ((j & 7) >> 1);
  const unsigned int* fb = g_flags + g * WGS_PER_GROUP * FSTRIDE;

  float creg = 0.0f;

  for (int t = 0; t < NSTEPS; ++t) {
    // ---- x-gather issued early (flies during the poll) ----
    const int idx = x[rowg * TT + t];
    const float xgv = Wxg[idx * HDIM + j];
    const float xiv = Wxi[idx * HDIM + j];
    const float xfv = Wxf[idx * HDIM + j];
    const float xov = Wxo[idx * HDIM + j];

    f32x4 acc[4] = {{0.f,0.f,0.f,0.f},{0.f,0.f,0.f,0.f},
                    {0.f,0.f,0.f,0.f},{0.f,0.f,0.f,0.f}};
    if (t > 0) {
      // ---- per-wave relaxed poll: lane l watches slot l&31 ----
      const unsigned int tgt = (unsigned int)t;
      for (;;) {
        const unsigned int v = __hip_atomic_load(
            fb + (lane & 31) * FSTRIDE, __ATOMIC_RELAXED,
            __HIP_MEMORY_SCOPE_AGENT);
        if (__all((int)(v >= tgt))) break;
        __builtin_amdgcn_s_sleep(1);
      }

      // ---- load A fragments (u64 coherence-point atomics) & MFMA ----
      const unsigned long long* srcq =
          g_hbuf + ((size_t)((t & 1) * NGROUPS + g)) * PGQ;
      unsigned long long q[4][4];
#pragma unroll
      for (int ksl = 0; ksl < 4; ++ksl) {
        const int base = ((wave << 2) + ksl) * 256 + (lane << 2);
#pragma unroll
        for (int u = 0; u < 4; ++u)
          q[ksl][u] = __hip_atomic_load(srcq + base + u, __ATOMIC_RELAXED,
                                        __HIP_MEMORY_SCOPE_AGENT);
      }
#pragma unroll
      for (int ksl = 0; ksl < 4; ++ksl) {
        u32x4 lo, hi;
#pragma unroll
        for (int u = 0; u < 4; ++u) {
          lo[u] = (unsigned int)q[ksl][u];
          hi[u] = (unsigned int)(q[ksl][u] >> 32);
        }
        const short8 a0 = __builtin_bit_cast(short8, lo);
        const short8 a1 = __builtin_bit_cast(short8, hi);
#pragma unroll
        for (int gate = 0; gate < 4; ++gate) {
          acc[gate] = __builtin_amdgcn_mfma_f32_16x16x32_bf16(a0, wf[gate][ksl][0], acc[gate], 0, 0, 0);
          acc[gate] = __builtin_amdgcn_mfma_f32_16x16x32_bf16(a0, wf[gate][ksl][1], acc[gate], 0, 0, 0);
          acc[gate] = __builtin_amdgcn_mfma_f32_16x16x32_bf16(a1, wf[gate][ksl][0], acc[gate], 0, 0, 0);
        }
      }
    }
    {
      const int crow = lanehi << 2;   // C/D: row=(lane>>4)*4+r, col=lane&15
#pragma unroll
      for (int gate = 0; gate < 4; ++gate)
#pragma unroll
        for (int r = 0; r < 4; ++r)
          part[wave][gate][crow + r][lane15] = acc[gate][r];
    }
    __syncthreads();

    // ---- elementwise: reduce partials, gates, cell, hidden ----
    const float pg = part[0][0][brow][jl] + part[1][0][brow][jl] +
                     part[2][0][brow][jl] + part[3][0][brow][jl] + xgv + bgv;
    const float pi = part[0][1][brow][jl] + part[1][1][brow][jl] +
                     part[2][1][brow][jl] + part[3][1][brow][jl] + xiv + biv;
    const float pf = part[0][2][brow][jl] + part[1][2][brow][jl] +
                     part[2][2][brow][jl] + part[3][2][brow][jl] + xfv + bfv;
    const float po = part[0][3][brow][jl] + part[1][3][brow][jl] +
                     part[2][3][brow][jl] + part[3][3][brow][jl] + xov + bov;
    const float gv = fast_tanh(pg);
    const float iv = fast_sigmoid(pi);
    const float fv = fast_sigmoid(pf);
    const float ov = fast_sigmoid(po);
    creg = gv * iv + creg * fv;
    const float hv = fast_tanh(creg) * ov;

    // 2-plane split; pack (j,j+1)x(plane0,plane1) into one u64; atomic store
    const unsigned short h0 = f32_to_bf16(hv);
    const unsigned short h1 = f32_to_bf16(hv - bf16_to_f32(h0));
    const unsigned int pa = (unsigned int)h0 | ((unsigned int)h1 << 16);
    const unsigned int na = (unsigned int)__shfl_xor((int)pa, 1);
    if (!(jl & 1)) {
      unsigned long long* dstq =
          g_hbuf + ((size_t)(((t + 1) & 1) * NGROUPS + g)) * PGQ;
      const unsigned int w0 = (pa & 0xffffu) | ((na & 0xffffu) << 16);   // plane0
      const unsigned int w1 = (pa >> 16) | (na & 0xffff0000u);           // plane1
      const unsigned long long v =
          (unsigned long long)w0 | ((unsigned long long)w1 << 32);
      __hip_atomic_store(dstq + pidx, v, __ATOMIC_RELAXED,
                         __HIP_MEMORY_SCOPE_AGENT);
    }
    __syncthreads();   // all waves' stores vmcnt-retired before flag post
    if (tid == 0) {
      __hip_atomic_store(g_flags + (g * WGS_PER_GROUP + w) * FSTRIDE,
                         (unsigned int)(t + 1), __ATOMIC_RELAXED,
                         __HIP_MEMORY_SCOPE_AGENT);
    }
  }

  // ---- epilogue: out = h^255 @ W_hp + b_p  (FLOAT32 output) ----
  {
    const unsigned int tgt = (unsigned int)NSTEPS;
    for (;;) {
      const unsigned int v = __hip_atomic_load(
          fb + (lane & 31) * FSTRIDE, __ATOMIC_RELAXED,
          __HIP_MEMORY_SCOPE_AGENT);
      if (__all((int)(v >= tgt))) break;
      __builtin_amdgcn_s_sleep(1);
    }
  }
  {
    const unsigned long long* srcq =
        g_hbuf + ((size_t)((NSTEPS & 1) * NGROUPS + g)) * PGQ;
    for (int i = tid; i < PGQ; i += 256)
      hfinq[i] = __hip_atomic_load(srcq + i, __ATOMIC_RELAXED,
                                   __HIP_MEMORY_SCOPE_AGENT);
  }
  __syncthreads();
  {
    const int bq = tid >> 4;
    const int q = tid & 15;
    const int cloc = q >> 2;
    const int ksl2 = q & 3;
    const int cc = (w << 2) + cloc;
    float sum = 0.0f;
    for (int k = ksl2 * 128; k < ksl2 * 128 + 128; ++k) {
      const int pk = ((k >> 5) << 8) + ((((k >> 3) & 3) << 4) + bq) * 4 + ((k & 7) >> 1);
      const unsigned long long qv = hfinq[pk];
      const unsigned int w0 = (unsigned int)qv;
      const unsigned int w1 = (unsigned int)(qv >> 32);
      const unsigned short s0 = (k & 1) ? (unsigned short)(w0 >> 16)
                                        : (unsigned short)(w0 & 0xffffu);
      const unsigned short s1 = (k & 1) ? (unsigned short)(w1 >> 16)
                                        : (unsigned short)(w1 & 0xffffu);
      const float hvf = bf16_to_f32(s0) + bf16_to_f32(s1);
      sum += hvf * Whp[k * CDIM + cc];
    }
    float* gb = &part[0][0][0][0];
    gb[tid] = sum;
    __syncthreads();
    if (ksl2 == 0) {
      const float res = gb[tid] + gb[tid + 1] + gb[tid + 2] + gb[tid + 3] + bp[cc];
      out[(g * 16 + bq) * CDIM + cc] = res;
    }
  }
}

extern "C" void kernel_launch(void* const* d_in, const int* in_sizes, int n_in,
                              void* d_out, int out_size, void* d_ws, size_t ws_size,
                              hipStream_t stream) {
  (void)in_sizes; (void)n_in; (void)out_size; (void)d_ws; (void)ws_size;
  const int* x = (const int*)d_in[0];
  const float* Wxg = (const float*)d_in[1];
  const float* Whg = (const float*)d_in[2];
  const float* Wxi = (const float*)d_in[3];
  const float* Whi = (const float*)d_in[4];
  const float* Wxf = (const float*)d_in[5];
  const float* Whf = (const float*)d_in[6];
  const float* Wxo = (const float*)d_in[7];
  const float* Who = (const float*)d_in[8];
  const float* Whp = (const float*)d_in[9];
  const float* bg = (const float*)d_in[10];
  const float* bi = (const float*)d_in[11];
  const float* bf = (const float*)d_in[12];
  const float* bo = (const float*)d_in[13];
  const float* bp = (const float*)d_in[14];
  float* out = (float*)d_out;

  void* flags_dev = nullptr;
  hipGetSymbolAddress(&flags_dev, HIP_SYMBOL(g_flags));
  hipMemsetAsync(flags_dev, 0,
                 sizeof(unsigned int) * NGROUPS * WGS_PER_GROUP * FSTRIDE,
                 stream);

  lstm_persistent<<<dim3(256), dim3(256), 0, stream>>>(
      x, Wxg, Whg, Wxi, Whi, Wxf, Whf, Wxo, Who, Whp,
      bg, bi, bf, bo, bp, out);
}